// Round 20
// baseline (47.208 us; speedup 1.0000x reference)
//
#include <hip/hip_runtime.h>

// exp(K), K = skew(theta) 64x64.  R20 = R19 VERBATIM except
// __launch_bounds__(256,4) -> (256,6).  Scheme (verified R19):
//   out = q0*I + q1*K + q2*K2 + K2*(q3*K + q4*K2)   (deg-4 matrix poly,
//   Bessel fit on [-1.9,1.9]; truncation ~0.011, measured absmax 0.0059)
// 3 phases / 2 barriers / 16 MFMA; B' = B^T = -q3*K + q4*K2 so
// mm_row(A2,B') = K2*(q3*K+q4*K2).  LDS 24KB.
//
// R20 rationale: every occupancy observation (R2/R5/R6/R8 ~38-42%) was
// taken with bound 4 or a register-starved kernel (R3/R7: 90+ live regs
// spilled at bound 5/6). R19 lives in ~52-56 VGPR -- first kernel where
// declaring 6 waves/EU (cap 85 >= 56, matching the 24KB-LDS 6-block
// limit) is feasible WITHOUT spill. Tests whether occupancy was
// resource-capped (expect 38->~60%, dur 47->~40us) or pinned by
// something else (neutral). Spill failure mode is detectable
// (FETCH/WRITE inflation) and revertible -- not the NaN class
// (launch_bounds edits passed in R4/R8).

typedef short s16x8 __attribute__((ext_vector_type(8)));
typedef float f32x4 __attribute__((ext_vector_type(4)));
typedef unsigned int u32;
typedef unsigned short u16;

#define NTH 2016
#define OFF_A    0
#define OFF_A2   8192
#define OFF_B    16384
#define LDS_BYTES 24576

// deg-4 matrix-poly coefficients, Bessel fit on [-1.9,1.9]
#define Q0C 0.998178f
#define Q1C 0.969932f
#define Q2C 0.490791f
#define Q3C 0.132293f
#define Q4C 0.034687f

__device__ __forceinline__ u32 cvtpk(float a, float b) {  // lo=bf16(a), hi=bf16(b)
    u32 d;
    asm("v_cvt_pk_bf16_f32 %0, %1, %2" : "=v"(d) : "v"(a), "v"(b));
    return d;
}
__device__ __forceinline__ float bflo(u32 w) { return __builtin_bit_cast(float, w << 16); }
__device__ __forceinline__ float bfhi(u32 w) { return __builtin_bit_cast(float, w & 0xFFFF0000u); }
__device__ __forceinline__ s16x8 cast8(uint4 v) { return __builtin_bit_cast(s16x8, v); }
// swizzled byte offset: row r, byte-in-row bo (<128). XOR touches bits 4..6 only.
__device__ __forceinline__ int swz(int r, int bo) { return r * 128 + (bo ^ ((r & 7) << 4)); }

__global__ __launch_bounds__(256, 6)
void so_poly4c(const float* __restrict__ theta, float* __restrict__ out) {
    __shared__ __align__(16) char sm[LDS_BYTES];
    const int tid = threadIdx.x;
    const int b   = blockIdx.x;
    const int l = tid & 63;
    const int w4 = tid >> 6;
    const int wr = w4 >> 1, wc = w4 & 1;
    const int q = l & 15, g = l >> 4;

    // ---- scatter: thread owns row=tid>>2, 16 cols; forward triangular map ----
    {
        const int row = tid >> 2, cb = (tid & 3) * 16;
        const float* th = theta + (size_t)b * NTH;
        const int offr = row * (127 - row) / 2;
        float v[16];
        #pragma unroll
        for (int k = 0; k < 16; ++k) {
            const int c = cb + k;
            const int au = offr + c - row - 1;              // upper: t-index of (row,c)
            const int al = c * (127 - c) / 2 + row - c - 1; // lower: t-index of (c,row)
            const int idx = (c > row) ? au : ((c < row) ? al : 0);
            const float t = th[idx];
            v[k] = (c > row) ? -t : ((c < row) ? t : 0.f);   // A = K (scale 1)
        }
        #pragma unroll
        for (int k = 0; k < 4; ++k) {
            uint2 u;
            u.x = cvtpk(v[4 * k + 0], v[4 * k + 1]);
            u.y = cvtpk(v[4 * k + 2], v[4 * k + 3]);
            *reinterpret_cast<uint2*>(sm + OFF_A + swz(row, 2 * cb + 8 * k)) = u;
        }
    }
    __syncthreads();   // (1)

    // frag loader: f[t][ks] = 8 bf16 (k-consec) from plane rows (rbase+16t+q)
    auto ld2 = [&](int plane, int rbase, s16x8 f[2][2]) {
        #pragma unroll
        for (int t = 0; t < 2; ++t) {
            const int r = rbase + 16 * t + q;
            const int a0 = swz(r, 16 * g);
            f[t][0] = cast8(*reinterpret_cast<const uint4*>(sm + plane + a0));
            f[t][1] = cast8(*reinterpret_cast<const uint4*>(sm + plane + (a0 ^ 64)));
        }
    };
    // row-ownership: ar[j][i] = (PA*PB^T)[32wr+16j+q][32wc+16i+4g+e]
    auto mm_row = [&](s16x8 fwr[2][2], s16x8 fwc[2][2], f32x4 ar[2][2]) {
        #pragma unroll
        for (int ks = 0; ks < 2; ++ks)
            #pragma unroll
            for (int j = 0; j < 2; ++j)
                #pragma unroll
                for (int i = 0; i < 2; ++i)
                    ar[j][i] = __builtin_amdgcn_mfma_f32_16x16x32_bf16(
                        fwc[i][ks], fwr[j][ks], ar[j][i], 0, 0, 0);
    };

    const f32x4 zf = {0.f, 0.f, 0.f, 0.f};
    s16x8 fwr[2][2], fwc[2][2];
    f32x4 ar[2][2];

    // ---- mm1: ar = A*A^T = -K2 (row-own) ; write A2 plane (= +K^2) and
    //          B' = -Q3C*K + Q4C*K2  (B' = B^T for B = q3*K + q4*K2) ----
    ar[0][0] = zf; ar[0][1] = zf; ar[1][0] = zf; ar[1][1] = zf;
    ld2(OFF_A, 32 * wr, fwr);
    ld2(OFF_A, 32 * wc, fwc);
    mm_row(fwr, fwc, ar);
    #pragma unroll
    for (int j = 0; j < 2; ++j)
        #pragma unroll
        for (int i = 0; i < 2; ++i) {
            const int r = 32 * wr + 16 * j + q, bo = 64 * wc + 32 * i + 8 * g;
            const uint2 ua = *reinterpret_cast<const uint2*>(sm + OFF_A + swz(r, bo));
            const float af[4] = {bflo(ua.x), bfhi(ua.x), bflo(ua.y), bfhi(ua.y)};
            float a2v[4], bv[4];
            #pragma unroll
            for (int e = 0; e < 4; ++e) {
                a2v[e] = -ar[j][i][e];                    // +K^2
                bv[e]  = a2v[e] * Q4C - af[e] * Q3C;      // B' = -q3*K + q4*K2
            }
            uint2 w2, wb;
            w2.x = cvtpk(a2v[0], a2v[1]); w2.y = cvtpk(a2v[2], a2v[3]);
            wb.x = cvtpk(bv[0], bv[1]);   wb.y = cvtpk(bv[2], bv[3]);
            *reinterpret_cast<uint2*>(sm + OFF_A2 + swz(r, bo)) = w2;
            *reinterpret_cast<uint2*>(sm + OFF_B  + swz(r, bo)) = wb;
        }
    __syncthreads();   // (2)

    // ---- mm2: ar = A2*B'^T = K2*(q3*K + q4*K2) = M (row-own) ;
    //          out = q0*I + q1*K + q2*K2 + M -> global, no sync ----
    ar[0][0] = zf; ar[0][1] = zf; ar[1][0] = zf; ar[1][1] = zf;
    ld2(OFF_A2, 32 * wr, fwr);
    ld2(OFF_B, 32 * wc, fwc);
    mm_row(fwr, fwc, ar);
    float* op = out + (size_t)b * 4096;
    #pragma unroll
    for (int j = 0; j < 2; ++j)
        #pragma unroll
        for (int i = 0; i < 2; ++i) {
            const int r = 32 * wr + 16 * j + q, bo = 64 * wc + 32 * i + 8 * g;
            const int c0 = 32 * wc + 16 * i + 4 * g;
            const uint2 ua  = *reinterpret_cast<const uint2*>(sm + OFF_A  + swz(r, bo));
            const uint2 ua2 = *reinterpret_cast<const uint2*>(sm + OFF_A2 + swz(r, bo));
            const float af[4]  = {bflo(ua.x),  bfhi(ua.x),  bflo(ua.y),  bfhi(ua.y)};
            const float a2f[4] = {bflo(ua2.x), bfhi(ua2.x), bflo(ua2.y), bfhi(ua2.y)};
            float4 o;
            o.x = ((r == c0 + 0) ? Q0C : 0.f) + Q1C * af[0] + Q2C * a2f[0] + ar[j][i][0];
            o.y = ((r == c0 + 1) ? Q0C : 0.f) + Q1C * af[1] + Q2C * a2f[1] + ar[j][i][1];
            o.z = ((r == c0 + 2) ? Q0C : 0.f) + Q1C * af[2] + Q2C * a2f[2] + ar[j][i][2];
            o.w = ((r == c0 + 3) ? Q0C : 0.f) + Q1C * af[3] + Q2C * a2f[3] + ar[j][i][3];
            *reinterpret_cast<float4*>(op + r * 64 + c0) = o;
        }
}

extern "C" void kernel_launch(void* const* d_in, const int* in_sizes, int n_in,
                              void* d_out, int out_size, void* d_ws, size_t ws_size,
                              hipStream_t stream) {
    const float* theta = (const float*)d_in[0];
    float* out = (float*)d_out;
    const int nbatch = in_sizes[0] / NTH;   // 8192
    so_poly4c<<<nbatch, 256, 0, stream>>>(theta, out);
}

// Round 21
// 46.528 us; speedup vs baseline: 1.0146x; 1.0146x over previous
//
#include <hip/hip_runtime.h>

// exp(K), K = skew(theta) 64x64.  R21 = R19 + register-carry of af/a2v
// across barrier (2).  Scheme (verified R19/R20):
//   out = q0*I + q1*K + q2*K2 + K2*(q3*K + q4*K2)   (deg-4 matrix poly,
//   Bessel fit on [-1.9,1.9]; measured absmax 0.0059, 3x margin)
// 3 phases / 2 barriers / 16 MFMA; B' = B^T = -q3*K + q4*K2 so
// mm_row(A2,B') = K2*(q3*K+q4*K2).  LDS 24KB.
//
// R21 change (R16/R17-proven carry pattern): mm1's epilogue already
// holds A (af_) and A2 (a2v_ = -ar) at row-own positions; carry both in
// fp32 regs across barrier (2) so mm2's epilogue reads NOTHING from LDS
// and skips the unpacks. VGPR ~56 -> ~88: launch_bounds(256,4) (cap 128;
// bound 6's cap 85 would spill, and R20 proved 6 is neutral anyway).
// Pre-commit: if neutral, kernel is at its structural limit (phase-
// minimal; TLP/occupancy/ILP levers all falsified) -- declare done.

typedef short s16x8 __attribute__((ext_vector_type(8)));
typedef float f32x4 __attribute__((ext_vector_type(4)));
typedef unsigned int u32;
typedef unsigned short u16;

#define NTH 2016
#define OFF_A    0
#define OFF_A2   8192
#define OFF_B    16384
#define LDS_BYTES 24576

// deg-4 matrix-poly coefficients, Bessel fit on [-1.9,1.9]
#define Q0C 0.998178f
#define Q1C 0.969932f
#define Q2C 0.490791f
#define Q3C 0.132293f
#define Q4C 0.034687f

__device__ __forceinline__ u32 cvtpk(float a, float b) {  // lo=bf16(a), hi=bf16(b)
    u32 d;
    asm("v_cvt_pk_bf16_f32 %0, %1, %2" : "=v"(d) : "v"(a), "v"(b));
    return d;
}
__device__ __forceinline__ float bflo(u32 w) { return __builtin_bit_cast(float, w << 16); }
__device__ __forceinline__ float bfhi(u32 w) { return __builtin_bit_cast(float, w & 0xFFFF0000u); }
__device__ __forceinline__ s16x8 cast8(uint4 v) { return __builtin_bit_cast(s16x8, v); }
// swizzled byte offset: row r, byte-in-row bo (<128). XOR touches bits 4..6 only.
__device__ __forceinline__ int swz(int r, int bo) { return r * 128 + (bo ^ ((r & 7) << 4)); }

__global__ __launch_bounds__(256, 4)
void so_poly4d(const float* __restrict__ theta, float* __restrict__ out) {
    __shared__ __align__(16) char sm[LDS_BYTES];
    const int tid = threadIdx.x;
    const int b   = blockIdx.x;
    const int l = tid & 63;
    const int w4 = tid >> 6;
    const int wr = w4 >> 1, wc = w4 & 1;
    const int q = l & 15, g = l >> 4;

    // ---- scatter: thread owns row=tid>>2, 16 cols; forward triangular map ----
    {
        const int row = tid >> 2, cb = (tid & 3) * 16;
        const float* th = theta + (size_t)b * NTH;
        const int offr = row * (127 - row) / 2;
        float v[16];
        #pragma unroll
        for (int k = 0; k < 16; ++k) {
            const int c = cb + k;
            const int au = offr + c - row - 1;              // upper: t-index of (row,c)
            const int al = c * (127 - c) / 2 + row - c - 1; // lower: t-index of (c,row)
            const int idx = (c > row) ? au : ((c < row) ? al : 0);
            const float t = th[idx];
            v[k] = (c > row) ? -t : ((c < row) ? t : 0.f);   // A = K (scale 1)
        }
        #pragma unroll
        for (int k = 0; k < 4; ++k) {
            uint2 u;
            u.x = cvtpk(v[4 * k + 0], v[4 * k + 1]);
            u.y = cvtpk(v[4 * k + 2], v[4 * k + 3]);
            *reinterpret_cast<uint2*>(sm + OFF_A + swz(row, 2 * cb + 8 * k)) = u;
        }
    }
    __syncthreads();   // (1)

    // frag loader: f[t][ks] = 8 bf16 (k-consec) from plane rows (rbase+16t+q)
    auto ld2 = [&](int plane, int rbase, s16x8 f[2][2]) {
        #pragma unroll
        for (int t = 0; t < 2; ++t) {
            const int r = rbase + 16 * t + q;
            const int a0 = swz(r, 16 * g);
            f[t][0] = cast8(*reinterpret_cast<const uint4*>(sm + plane + a0));
            f[t][1] = cast8(*reinterpret_cast<const uint4*>(sm + plane + (a0 ^ 64)));
        }
    };
    // row-ownership: ar[j][i] = (PA*PB^T)[32wr+16j+q][32wc+16i+4g+e]
    auto mm_row = [&](s16x8 fwr[2][2], s16x8 fwc[2][2], f32x4 ar[2][2]) {
        #pragma unroll
        for (int ks = 0; ks < 2; ++ks)
            #pragma unroll
            for (int j = 0; j < 2; ++j)
                #pragma unroll
                for (int i = 0; i < 2; ++i)
                    ar[j][i] = __builtin_amdgcn_mfma_f32_16x16x32_bf16(
                        fwc[i][ks], fwr[j][ks], ar[j][i], 0, 0, 0);
    };

    const f32x4 zf = {0.f, 0.f, 0.f, 0.f};
    s16x8 fwr[2][2], fwc[2][2];
    f32x4 ar[2][2];
    float af_[2][2][4], a2v_[2][2][4];   // A, K^2 at row-own positions (carried mm1->mm2)

    // ---- mm1: ar = A*A^T = -K2 (row-own) ; write A2 plane (= +K^2) and
    //          B' = -Q3C*K + Q4C*K2 ; keep af_/a2v_ in regs ----
    ar[0][0] = zf; ar[0][1] = zf; ar[1][0] = zf; ar[1][1] = zf;
    ld2(OFF_A, 32 * wr, fwr);
    ld2(OFF_A, 32 * wc, fwc);
    mm_row(fwr, fwc, ar);
    #pragma unroll
    for (int j = 0; j < 2; ++j)
        #pragma unroll
        for (int i = 0; i < 2; ++i) {
            const int r = 32 * wr + 16 * j + q, bo = 64 * wc + 32 * i + 8 * g;
            const uint2 ua = *reinterpret_cast<const uint2*>(sm + OFF_A + swz(r, bo));
            af_[j][i][0] = bflo(ua.x); af_[j][i][1] = bfhi(ua.x);
            af_[j][i][2] = bflo(ua.y); af_[j][i][3] = bfhi(ua.y);
            float bv[4];
            #pragma unroll
            for (int e = 0; e < 4; ++e) {
                a2v_[j][i][e] = -ar[j][i][e];                       // +K^2
                bv[e] = a2v_[j][i][e] * Q4C - af_[j][i][e] * Q3C;   // B' = -q3*K + q4*K2
            }
            uint2 w2, wb;
            w2.x = cvtpk(a2v_[j][i][0], a2v_[j][i][1]); w2.y = cvtpk(a2v_[j][i][2], a2v_[j][i][3]);
            wb.x = cvtpk(bv[0], bv[1]);                 wb.y = cvtpk(bv[2], bv[3]);
            *reinterpret_cast<uint2*>(sm + OFF_A2 + swz(r, bo)) = w2;
            *reinterpret_cast<uint2*>(sm + OFF_B  + swz(r, bo)) = wb;
        }
    __syncthreads();   // (2)

    // ---- mm2: ar = A2*B'^T = K2*(q3*K + q4*K2) = M (row-own) ;
    //          out = q0*I + q1*K + q2*K2 + M -> global (no LDS in epilogue) ----
    ar[0][0] = zf; ar[0][1] = zf; ar[1][0] = zf; ar[1][1] = zf;
    ld2(OFF_A2, 32 * wr, fwr);
    ld2(OFF_B, 32 * wc, fwc);
    mm_row(fwr, fwc, ar);
    float* op = out + (size_t)b * 4096;
    #pragma unroll
    for (int j = 0; j < 2; ++j)
        #pragma unroll
        for (int i = 0; i < 2; ++i) {
            const int r = 32 * wr + 16 * j + q, c0 = 32 * wc + 16 * i + 4 * g;
            float4 o;
            o.x = ((r == c0 + 0) ? Q0C : 0.f) + Q1C * af_[j][i][0] + Q2C * a2v_[j][i][0] + ar[j][i][0];
            o.y = ((r == c0 + 1) ? Q0C : 0.f) + Q1C * af_[j][i][1] + Q2C * a2v_[j][i][1] + ar[j][i][1];
            o.z = ((r == c0 + 2) ? Q0C : 0.f) + Q1C * af_[j][i][2] + Q2C * a2v_[j][i][2] + ar[j][i][2];
            o.w = ((r == c0 + 3) ? Q0C : 0.f) + Q1C * af_[j][i][3] + Q2C * a2v_[j][i][3] + ar[j][i][3];
            *reinterpret_cast<float4*>(op + r * 64 + c0) = o;
        }
}

extern "C" void kernel_launch(void* const* d_in, const int* in_sizes, int n_in,
                              void* d_out, int out_size, void* d_ws, size_t ws_size,
                              hipStream_t stream) {
    const float* theta = (const float*)d_in[0];
    float* out = (float*)d_out;
    const int nbatch = in_sizes[0] / NTH;   // 8192
    so_poly4d<<<nbatch, 256, 0, stream>>>(theta, out);
}